// Round 2
// baseline (1218.990 us; speedup 1.0000x reference)
//
#include <hip/hip_runtime.h>
#include <hip/hip_bf16.h>
#include <math.h>

#define HEADS 8
#define DKEY 64
#define DVAL 192
#define SEQ 2048
#define DIMM 1536
#define NREL 192
#define NB 32
#define TDIST (2*SEQ-1)   // 4095

// ---------------------------------------------------------------------------
// Positional embedding: pos[t][0..191], t=0..4094, distance = t-2047
// ---------------------------------------------------------------------------
__global__ void pos_embed_kernel(float* __restrict__ pos) {
    int t = blockIdx.x;
    int f = threadIdx.x;          // 0..63, only 0..31 active for features
    float dist = (float)(t - (SEQ - 1));
    float absd = fabsf(dist);
    float sgn  = (dist > 0.0f) ? 1.0f : ((dist < 0.0f) ? -1.0f : 0.0f);
    float e = 0.0f, c = 0.0f, g = 0.0f;
    if (f < NB) {
        // feat_exp: half_life = 2^linspace(3, 11, 32)
        float hl = exp2f(3.0f + 8.0f * (float)f / 31.0f);
        e = exp2f(-absd / hl);
        // feat_cm: center_width = 2^(f+1) - 1, strict >
        float cw = exp2f((float)(f + 1)) - 1.0f;
        c = (cw > absd) ? 1.0f : 0.0f;
        // feat_gamma: mean = 64*(f+1), stddev = 32
        double conc = (double)(4 * (f + 1) * (f + 1));   // (mean/std)^2
        double rate = ((double)(f + 1)) / 16.0;          // mean/std^2
        // xlogy(conc-1, absd): first arg > 0 always, so absd==0 gives
        // (conc-1)*log(0) = -inf  (NOT the xlogy zero special case!)
        double lu = (absd > 0.0f)
            ? ((conc - 1.0) * log((double)absd) - rate * (double)absd)
            : -INFINITY;
        double ln = lgamma(conc) - conc * log(rate);
        g = (float)exp(lu - ln) + 1e-8f;   // at absd==0: exactly 1e-8 for all f
    }
    // max over the 32 gamma features (lanes 0..31)
    float gm = g;
    #pragma unroll
    for (int off = 16; off >= 1; off >>= 1)
        gm = fmaxf(gm, __shfl_xor(gm, off, 32));
    if (f < NB) {
        float* row = pos + (size_t)t * NREL;
        g = g / gm;
        row[f]            = e;
        row[NB + f]       = c;
        row[2 * NB + f]   = g;
        row[96 + f]           = sgn * e;
        row[96 + NB + f]      = sgn * c;
        row[96 + 2 * NB + f]  = sgn * g;
    }
}

// ---------------------------------------------------------------------------
// f32 tiled GEMM: C[M,N] = alpha*(A[M,K]@B[K,N]) (+ bias[n])
// BM=128, BN=64, BK=16, 256 threads, 8x4 microtile.
// ---------------------------------------------------------------------------
__global__ __launch_bounds__(256) void gemm_f32(
    const float* __restrict__ A, const float* __restrict__ B,
    float* __restrict__ C, const float* __restrict__ bias,
    int M, int N, int K, float alpha)
{
    __shared__ float As[16][128];   // [k][m] transposed
    __shared__ float Bs[16][64];    // [k][n]
    const int tid = threadIdx.x;
    const int tx = tid & 15;        // n microtile: cols tx*4..tx*4+3
    const int ty = tid >> 4;        // m microtile: rows ty*8..ty*8+7
    const int m0 = blockIdx.y * 128;
    const int n0 = blockIdx.x * 64;
    const int am = tid >> 1;            // A row within tile
    const int ak = (tid & 1) * 8;       // A k-segment
    const int bk = tid >> 4;            // B row within tile
    const int bn = (tid & 15) * 4;      // B cols

    float acc[8][4];
    #pragma unroll
    for (int i = 0; i < 8; ++i)
        #pragma unroll
        for (int j = 0; j < 4; ++j) acc[i][j] = 0.0f;

    for (int k0 = 0; k0 < K; k0 += 16) {
        float4 a0 = make_float4(0.f,0.f,0.f,0.f), a1 = a0;
        int gm = m0 + am;
        if (gm < M) {
            const float* ap = A + (size_t)gm * K + (k0 + ak);
            a0 = *(const float4*)(ap);
            a1 = *(const float4*)(ap + 4);
        }
        float4 bb = *(const float4*)(B + (size_t)(k0 + bk) * N + (n0 + bn));
        __syncthreads();   // previous iteration's LDS reads complete
        As[ak+0][am] = a0.x; As[ak+1][am] = a0.y;
        As[ak+2][am] = a0.z; As[ak+3][am] = a0.w;
        As[ak+4][am] = a1.x; As[ak+5][am] = a1.y;
        As[ak+6][am] = a1.z; As[ak+7][am] = a1.w;
        *(float4*)&Bs[bk][bn] = bb;
        __syncthreads();
        #pragma unroll
        for (int kk = 0; kk < 16; ++kk) {
            const float4 av0 = *(const float4*)&As[kk][ty*8];
            const float4 av1 = *(const float4*)&As[kk][ty*8+4];
            const float4 bv  = *(const float4*)&Bs[kk][tx*4];
            float a8[8] = {av0.x,av0.y,av0.z,av0.w,av1.x,av1.y,av1.z,av1.w};
            float b4[4] = {bv.x,bv.y,bv.z,bv.w};
            #pragma unroll
            for (int i = 0; i < 8; ++i)
                #pragma unroll
                for (int j = 0; j < 4; ++j)
                    acc[i][j] = fmaf(a8[i], b4[j], acc[i][j]);
        }
    }
    #pragma unroll
    for (int i = 0; i < 8; ++i) {
        int gm = m0 + ty*8 + i;
        if (gm < M) {
            float* cp = C + (size_t)gm * N + n0 + tx*4;
            #pragma unroll
            for (int j = 0; j < 4; ++j) {
                float vv = alpha * acc[i][j];
                if (bias) vv += bias[n0 + tx*4 + j];
                cp[j] = vv;
            }
        }
    }
}

// ---------------------------------------------------------------------------
// Flash attention with shifted relative logits.
// Block = (head h, 32 query rows). K-tile = 64 keys.
// S[i][j] = qc[i]*k[j] + (qc[i]+dlt)*rel[j-i+31]   (qc = q*scale + cbias,
//           dlt = pbias - cbias, rel rows staged from relk[j0-i0+2016 + r])
// ---------------------------------------------------------------------------
#define QB 32
#define KB 64
#define RR 95      // KB + QB - 1
#define LPAD 68    // row stride (floats) for 64-wide LDS arrays; 68/4=17 odd
#define SPAD 65

__global__ __launch_bounds__(256) void attn_kernel(
    const float* __restrict__ qs,   // [2048][512], pre-scaled by 1/8
    const float* __restrict__ ks,   // [2048][512]
    const float* __restrict__ vs,   // [2048][1536]
    const float* __restrict__ relk, // [4095][512]
    const float* __restrict__ cbias,// [8][64]
    const float* __restrict__ pbias,// [8][64]
    float* __restrict__ o)          // [2048][1536]
{
    const int h  = blockIdx.x & (HEADS - 1);
    const int i0 = (blockIdx.x >> 3) * QB;

    __shared__ float qc[QB][LPAD];
    __shared__ float kt[KB][LPAD];
    __shared__ float rel[RR][LPAD];
    __shared__ float S[QB][SPAD];
    __shared__ float dlt[DKEY];
    __shared__ float red[QB][9];
    __shared__ float mrow[QB], lrow[QB], arow[QB];

    const int tid = threadIdx.x;

    if (tid < QB) { mrow[tid] = -INFINITY; lrow[tid] = 0.0f; }
    if (tid < DKEY) dlt[tid] = pbias[h*DKEY + tid] - cbias[h*DKEY + tid];
    for (int idx = tid; idx < QB * 16; idx += 256) {
        int r = idx >> 4, dq = (idx & 15) * 4;
        float4 qv = *(const float4*)(qs + (size_t)(i0 + r) * (HEADS*DKEY) + h*DKEY + dq);
        const float* cb = cbias + h*DKEY + dq;
        qv.x += cb[0]; qv.y += cb[1]; qv.z += cb[2]; qv.w += cb[3];
        *(float4*)&qc[r][dq] = qv;
    }

    // S-compute mapping: i = ti + 8*ii (strided rows -> both parities of j-i
    // across lanes -> rel reads spread over bank quads), j = 2*tj + jj
    const int ti = tid & 7;
    const int tj = tid >> 3;      // 0..31
    // PV mapping
    const int c  = tid & 63;
    const int rg = tid >> 6;      // rows rg*8..rg*8+7

    float acc[8][3];
    #pragma unroll
    for (int ii = 0; ii < 8; ++ii) { acc[ii][0]=0.f; acc[ii][1]=0.f; acc[ii][2]=0.f; }

    for (int j0 = 0; j0 < SEQ; j0 += KB) {
        __syncthreads();
        // ---- stage K tile ----
        for (int idx = tid; idx < KB * 16; idx += 256) {
            int r = idx >> 4, dq = (idx & 15) * 4;
            *(float4*)&kt[r][dq] =
                *(const float4*)(ks + (size_t)(j0 + r)*(HEADS*DKEY) + h*DKEY + dq);
        }
        // ---- stage rel tile: rows base..base+94, base = j0-i0+2016 ----
        int base = j0 - i0 + (SEQ - QB);
        for (int idx = tid; idx < RR * 16; idx += 256) {
            int r = idx >> 4, dq = (idx & 15) * 4;
            *(float4*)&rel[r][dq] =
                *(const float4*)(relk + (size_t)(base + r)*(HEADS*DKEY) + h*DKEY + dq);
        }
        __syncthreads();

        // ---- compute S (content + rel) ----
        {
            float s[4][2];
            #pragma unroll
            for (int ii = 0; ii < 4; ++ii) { s[ii][0] = 0.f; s[ii][1] = 0.f; }
            const float* qrow[4];
            const float* krow[2];
            const float* rrow[4][2];
            #pragma unroll
            for (int ii = 0; ii < 4; ++ii) qrow[ii] = &qc[ti + 8*ii][0];
            #pragma unroll
            for (int jj = 0; jj < 2; ++jj) krow[jj] = &kt[2*tj + jj][0];
            #pragma unroll
            for (int ii = 0; ii < 4; ++ii)
                #pragma unroll
                for (int jj = 0; jj < 2; ++jj)
                    rrow[ii][jj] = &rel[(2*tj + jj) - (ti + 8*ii) + (QB - 1)][0];

            #pragma unroll 4
            for (int dq = 0; dq < DKEY; dq += 4) {
                float4 dv = *(const float4*)&dlt[dq];
                float4 qv[4], qp[4];
                #pragma unroll
                for (int ii = 0; ii < 4; ++ii) {
                    qv[ii] = *(const float4*)(qrow[ii] + dq);
                    qp[ii].x = qv[ii].x + dv.x; qp[ii].y = qv[ii].y + dv.y;
                    qp[ii].z = qv[ii].z + dv.z; qp[ii].w = qv[ii].w + dv.w;
                }
                float4 kv[2];
                kv[0] = *(const float4*)(krow[0] + dq);
                kv[1] = *(const float4*)(krow[1] + dq);
                #pragma unroll
                for (int ii = 0; ii < 4; ++ii)
                    #pragma unroll
                    for (int jj = 0; jj < 2; ++jj) {
                        float4 rv = *(const float4*)(rrow[ii][jj] + dq);
                        float t0 = s[ii][jj];
                        t0 = fmaf(qv[ii].x, kv[jj].x, t0);
                        t0 = fmaf(qv[ii].y, kv[jj].y, t0);
                        t0 = fmaf(qv[ii].z, kv[jj].z, t0);
                        t0 = fmaf(qv[ii].w, kv[jj].w, t0);
                        t0 = fmaf(qp[ii].x, rv.x, t0);
                        t0 = fmaf(qp[ii].y, rv.y, t0);
                        t0 = fmaf(qp[ii].z, rv.z, t0);
                        t0 = fmaf(qp[ii].w, rv.w, t0);
                        s[ii][jj] = t0;
                    }
            }
            #pragma unroll
            for (int ii = 0; ii < 4; ++ii)
                #pragma unroll
                for (int jj = 0; jj < 2; ++jj)
                    S[ti + 8*ii][2*tj + jj] = s[ii][jj];
        }
        __syncthreads();

        // ---- online softmax: row max ----
        {
            int i = tid & 31, seg = tid >> 5;
            float mx = -INFINITY;
            #pragma unroll
            for (int j = 0; j < 8; ++j) mx = fmaxf(mx, S[i][seg*8 + j]);
            red[i][seg] = mx;
        }
        __syncthreads();
        if (tid < QB) {
            float mold = mrow[tid];
            float mx = mold;
            #pragma unroll
            for (int sg = 0; sg < 8; ++sg) mx = fmaxf(mx, red[tid][sg]);
            arow[tid] = (mold == -INFINITY) ? 0.0f : __expf(mold - mx);
            mrow[tid] = mx;
        }
        __syncthreads();
        // ---- p = exp(S - m), partial sums ----
        {
            int i = tid & 31, seg = tid >> 5;
            float m = mrow[i];
            float sum = 0.0f;
            #pragma unroll
            for (int j = 0; j < 8; ++j) {
                float p = __expf(S[i][seg*8 + j] - m);
                S[i][seg*8 + j] = p;
                sum += p;
            }
            red[i][seg] = sum;
        }
        __syncthreads();
        if (tid < QB) {
            float sm = 0.0f;
            #pragma unroll
            for (int sg = 0; sg < 8; ++sg) sm += red[tid][sg];
            lrow[tid] = lrow[tid] * arow[tid] + sm;
        }
        // ---- PV accumulate (concurrent with l-update; disjoint data) ----
        {
            #pragma unroll
            for (int ii = 0; ii < 8; ++ii) {
                float a = arow[rg*8 + ii];
                acc[ii][0] *= a; acc[ii][1] *= a; acc[ii][2] *= a;
            }
            #pragma unroll 4
            for (int j = 0; j < KB; ++j) {
                const float* vp = vs + (size_t)(j0 + j)*(HEADS*DVAL) + h*DVAL + c;
                float v0 = vp[0], v1 = vp[64], v2 = vp[128];
                #pragma unroll
                for (int ii = 0; ii < 8; ++ii) {
                    float p = S[rg*8 + ii][j];
                    acc[ii][0] = fmaf(p, v0, acc[ii][0]);
                    acc[ii][1] = fmaf(p, v1, acc[ii][1]);
                    acc[ii][2] = fmaf(p, v2, acc[ii][2]);
                }
            }
        }
    }
    __syncthreads();   // lrow final values visible
    #pragma unroll
    for (int ii = 0; ii < 8; ++ii) {
        float inv = 1.0f / lrow[rg*8 + ii];
        float* op = o + (size_t)(i0 + rg*8 + ii)*(HEADS*DVAL) + h*DVAL + c;
        op[0]   = acc[ii][0] * inv;
        op[64]  = acc[ii][1] * inv;
        op[128] = acc[ii][2] * inv;
    }
}

// ---------------------------------------------------------------------------
extern "C" void kernel_launch(void* const* d_in, const int* in_sizes, int n_in,
                              void* d_out, int out_size, void* d_ws, size_t ws_size,
                              hipStream_t stream)
{
    const float* x     = (const float*)d_in[0];
    const float* Wq    = (const float*)d_in[1];
    const float* Wk    = (const float*)d_in[2];
    const float* Wv    = (const float*)d_in[3];
    const float* Wrel  = (const float*)d_in[4];
    const float* cbias = (const float*)d_in[5];
    const float* pbias = (const float*)d_in[6];
    const float* Wo    = (const float*)d_in[7];
    const float* bo    = (const float*)d_in[8];
    float* out = (float*)d_out;

    float* ws   = (float*)d_ws;
    float* q    = ws;                               // 2048*512
    float* k    = q   + (size_t)SEQ * 512;          // 2048*512
    float* v    = k   + (size_t)SEQ * 512;          // 2048*1536
    float* pos  = v   + (size_t)SEQ * DIMM;         // 4095*192
    float* relk = pos + (size_t)TDIST * NREL;       // 4095*512
    float* ao   = relk+ (size_t)TDIST * 512;        // 2048*1536
    // total ~45 MB of f32 workspace

    pos_embed_kernel<<<dim3(TDIST), dim3(64), 0, stream>>>(pos);

    // q = (x@Wq) * scale, scale = 64^-0.5 = 0.125
    gemm_f32<<<dim3(512/64, SEQ/128), 256, 0, stream>>>(
        x, Wq, q, nullptr, SEQ, 512, DIMM, 0.125f);
    gemm_f32<<<dim3(512/64, SEQ/128), 256, 0, stream>>>(
        x, Wk, k, nullptr, SEQ, 512, DIMM, 1.0f);
    gemm_f32<<<dim3(DIMM/64, SEQ/128), 256, 0, stream>>>(
        x, Wv, v, nullptr, SEQ, DIMM, DIMM, 1.0f);
    gemm_f32<<<dim3(512/64, (TDIST + 127)/128), 256, 0, stream>>>(
        pos, Wrel, relk, nullptr, TDIST, 512, NREL, 1.0f);

    attn_kernel<<<dim3(HEADS * (SEQ/QB)), 256, 0, stream>>>(
        q, k, v, relk, cbias, pbias, ao);

    gemm_f32<<<dim3(DIMM/64, SEQ/128), 256, 0, stream>>>(
        ao, Wo, out, bo, SEQ, DIMM, DIMM, 1.0f);
}

// Round 3
// 693.308 us; speedup vs baseline: 1.7582x; 1.7582x over previous
//
#include <hip/hip_runtime.h>
#include <math.h>

#define HEADS 8
#define DKEY 64
#define DVAL 192
#define SEQ 2048
#define DIMM 1536
#define NREL 192
#define NB 32
#define TDIST (2*SEQ-1)   // 4095
#define QKSTR 1024        // row stride of fused [q|k] buffer

typedef __attribute__((ext_vector_type(8))) short short8v;   // bf16x8 MFMA frag
typedef __attribute__((ext_vector_type(4))) float f32x4;
typedef __attribute__((ext_vector_type(4))) unsigned short ushort4v;

__device__ __forceinline__ unsigned short f2bf(float f) {
    unsigned int u = __float_as_uint(f);
    u += 0x7FFFu + ((u >> 16) & 1u);          // RNE
    return (unsigned short)(u >> 16);
}
__device__ __forceinline__ float bf2f(unsigned short h) {
    return __uint_as_float(((unsigned int)h) << 16);
}

#define GLOAD16(gp, lp) __builtin_amdgcn_global_load_lds( \
    (const __attribute__((address_space(1))) void*)(gp),  \
    (__attribute__((address_space(3))) void*)(lp), 16, 0, 0)

// ---------------------------------------------------------------------------
// Positional embedding -> bf16 [4096][192]; row 4095 zeroed (pad row).
// ---------------------------------------------------------------------------
__global__ void pos_embed_kernel(unsigned short* __restrict__ posb) {
    int t = blockIdx.x;           // 0..4095
    int f = threadIdx.x;
    if (f >= NB) return;
    unsigned short* row = posb + (size_t)t * NREL;
    if (t >= TDIST) {             // pad row: zeros
        row[f] = 0; row[NB+f] = 0; row[2*NB+f] = 0;
        row[96+f] = 0; row[96+NB+f] = 0; row[96+2*NB+f] = 0;
        return;
    }
    float dist = (float)(t - (SEQ - 1));
    float absd = fabsf(dist);
    float sgn  = (dist > 0.0f) ? 1.0f : ((dist < 0.0f) ? -1.0f : 0.0f);
    // feat_exp
    float hl = exp2f(3.0f + 8.0f * (float)f / 31.0f);
    float e = exp2f(-absd / hl);
    // feat_cm
    float cw = exp2f((float)(f + 1)) - 1.0f;
    float c = (cw > absd) ? 1.0f : 0.0f;
    // feat_gamma (f64; xlogy(conc-1, 0) = -inf since conc-1 > 0)
    double conc = (double)(4 * (f + 1) * (f + 1));
    double rate = ((double)(f + 1)) / 16.0;
    double lu = (absd > 0.0f)
        ? ((conc - 1.0) * log((double)absd) - rate * (double)absd)
        : -INFINITY;
    double ln = lgamma(conc) - conc * log(rate);
    float g = (float)exp(lu - ln) + 1e-8f;
    float gm = g;
    #pragma unroll
    for (int off = 16; off >= 1; off >>= 1)
        gm = fmaxf(gm, __shfl_xor(gm, off, 32));
    g = g / gm;
    row[f]           = f2bf(e);
    row[NB + f]      = f2bf(c);
    row[2*NB + f]    = f2bf(g);
    row[96 + f]      = f2bf(sgn * e);
    row[96 + NB + f] = f2bf(sgn * c);
    row[96 + 2*NB+f] = f2bf(sgn * g);
}

// ---------------------------------------------------------------------------
// x f32 -> hi/lo bf16 split (row-major, vectorized)
// ---------------------------------------------------------------------------
__global__ __launch_bounds__(256) void cast_hilo(
    const float4* __restrict__ in, ushort4v* __restrict__ hi,
    ushort4v* __restrict__ lo, int n4)
{
    int i = blockIdx.x * 256 + threadIdx.x;
    if (i >= n4) return;
    float4 v = in[i];
    unsigned short h0 = f2bf(v.x), h1 = f2bf(v.y), h2 = f2bf(v.z), h3 = f2bf(v.w);
    hi[i] = (ushort4v){h0, h1, h2, h3};
    lo[i] = (ushort4v){ f2bf(v.x - bf2f(h0)), f2bf(v.y - bf2f(h1)),
                        f2bf(v.z - bf2f(h2)), f2bf(v.w - bf2f(h3)) };
}

// ---------------------------------------------------------------------------
// W f32 [R][C] -> hiT (,loT) bf16 [C][R], optionally pre-scaled.
// R,C multiples of 32. Block 256, tile 32x32 via LDS.
// ---------------------------------------------------------------------------
__global__ __launch_bounds__(256) void castT_kernel(
    const float* __restrict__ in, unsigned short* __restrict__ hiT,
    unsigned short* __restrict__ loT, int R, int C, float scale)
{
    __shared__ float t[32][33];
    int c0 = blockIdx.x * 32, r0 = blockIdx.y * 32;
    int tx = threadIdx.x & 31, ty = threadIdx.x >> 5;   // ty 0..7
    #pragma unroll
    for (int rr = ty; rr < 32; rr += 8)
        t[rr][tx] = in[(size_t)(r0 + rr) * C + c0 + tx] * scale;
    __syncthreads();
    #pragma unroll
    for (int cc = ty; cc < 32; cc += 8) {
        float v = t[tx][cc];                      // in[r0+tx][c0+cc]
        unsigned short h = f2bf(v);
        size_t oi = (size_t)(c0 + cc) * R + r0 + tx;
        hiT[oi] = h;
        if (loT) loT[oi] = f2bf(v - bf2f(h));
    }
}

// ---------------------------------------------------------------------------
// bf16 MFMA GEMM: C[M][N] f32 = A[M][K] @ Bt[N][K]^T (+bias[n]).
// 128x128 tile, BK=32, 256 thr = 4 waves (2x2 of 64x64), 16x16x32 MFMA.
// LDS XOR-swizzle: chunk ^= (row>>2)&3, applied on pre-swizzled global src
// (global_load_lds dest is linear) and on ds_read addresses (involution).
// M,N %128 == 0; K %32 == 0. All row strides 16B-aligned.
// ---------------------------------------------------------------------------
__global__ __launch_bounds__(256) void gemm_bf16(
    const unsigned short* __restrict__ A, const unsigned short* __restrict__ Bt,
    float* __restrict__ C, const float* __restrict__ bias,
    int M, int N, int K)
{
    __shared__ unsigned short Als[128 * 32];
    __shared__ unsigned short Bls[128 * 32];
    const int tid  = threadIdx.x;
    const int lane = tid & 63;
    const int wave = tid >> 6;
    const int wr = (wave >> 1) * 64, wc = (wave & 1) * 64;
    const int m0 = blockIdx.y * 128, n0 = blockIdx.x * 128;

    // staging: wave covers rows [wave*32, wave*32+32) in 2 instrs of 16 rows
    const int sr = lane >> 2;                                  // row in group
    const int sc = (((lane & 3) ^ ((lane >> 4) & 3))) * 8;     // swz src chunk
    const unsigned short* gA0 = A  + (size_t)(m0 + wave*32 + sr) * K + sc;
    const unsigned short* gB0 = Bt + (size_t)(n0 + wave*32 + sr) * K + sc;
    unsigned short* lA0 = &Als[(wave*32) * 32];
    unsigned short* lA1 = &Als[(wave*32 + 16) * 32];
    unsigned short* lB0 = &Bls[(wave*32) * 32];
    unsigned short* lB1 = &Bls[(wave*32 + 16) * 32];

    // fragment reads: row = (wr|wc) + mf*16 + frow, chunk = (lane>>4)^quad(row)
    const int frow = lane & 15;
    const int rchunk = (((lane >> 4) ^ ((frow >> 2) & 3))) * 8;

    f32x4 acc[4][4] = {};

    for (int k0 = 0; k0 < K; k0 += 32) {
        __syncthreads();
        GLOAD16(gA0 + k0, lA0);
        GLOAD16(gA0 + k0 + (size_t)16 * K, lA1);
        GLOAD16(gB0 + k0, lB0);
        GLOAD16(gB0 + k0 + (size_t)16 * K, lB1);
        __syncthreads();
        short8v af[4], bf[4];
        #pragma unroll
        for (int mf = 0; mf < 4; ++mf)
            af[mf] = *(const short8v*)&Als[(wr + mf*16 + frow) * 32 + rchunk];
        #pragma unroll
        for (int nf = 0; nf < 4; ++nf)
            bf[nf] = *(const short8v*)&Bls[(wc + nf*16 + frow) * 32 + rchunk];
        #pragma unroll
        for (int mf = 0; mf < 4; ++mf)
            #pragma unroll
            for (int nf = 0; nf < 4; ++nf)
                acc[mf][nf] = __builtin_amdgcn_mfma_f32_16x16x32_bf16(
                    af[mf], bf[nf], acc[mf][nf], 0, 0, 0);
    }

    const int er = ((lane >> 4) << 2);      // + mf*16 + r
    const int ec = lane & 15;               // + nf*16
    #pragma unroll
    for (int nf = 0; nf < 4; ++nf) {
        const int col = n0 + wc + nf*16 + ec;
        const float bv = bias ? bias[col] : 0.0f;
        #pragma unroll
        for (int mf = 0; mf < 4; ++mf) {
            const int row = m0 + wr + mf*16 + er;
            #pragma unroll
            for (int r = 0; r < 4; ++r)
                C[(size_t)(row + r) * N + col] = acc[mf][nf][r] + bv;
        }
    }
}

// ---------------------------------------------------------------------------
// Split-precision bf16 GEMM: C = (Ah+Al)(Bh+Bl)^T - Al*Bl  (3 MFMA passes).
// Error ~1e-4 relative — f32-grade logits from bf16 matrix cores.
// ---------------------------------------------------------------------------
__global__ __launch_bounds__(256) void gemm_bf16_split(
    const unsigned short* __restrict__ Ah, const unsigned short* __restrict__ Alo,
    const unsigned short* __restrict__ Bh, const unsigned short* __restrict__ Blo,
    float* __restrict__ C, int M, int N, int K)
{
    __shared__ unsigned short sAh[128*32], sAl[128*32], sBh[128*32], sBl[128*32];
    const int tid  = threadIdx.x;
    const int lane = tid & 63;
    const int wave = tid >> 6;
    const int wr = (wave >> 1) * 64, wc = (wave & 1) * 64;
    const int m0 = blockIdx.y * 128, n0 = blockIdx.x * 128;

    const int sr = lane >> 2;
    const int sc = (((lane & 3) ^ ((lane >> 4) & 3))) * 8;
    const size_t aoff = (size_t)(m0 + wave*32 + sr) * K + sc;
    const size_t boff = (size_t)(n0 + wave*32 + sr) * K + sc;
    const int l0 = (wave*32) * 32, l1 = (wave*32 + 16) * 32;

    const int frow = lane & 15;
    const int rchunk = (((lane >> 4) ^ ((frow >> 2) & 3))) * 8;

    f32x4 acc[4][4] = {};

    for (int k0 = 0; k0 < K; k0 += 32) {
        __syncthreads();
        GLOAD16(Ah  + aoff + k0, &sAh[l0]); GLOAD16(Ah  + aoff + k0 + (size_t)16*K, &sAh[l1]);
        GLOAD16(Alo + aoff + k0, &sAl[l0]); GLOAD16(Alo + aoff + k0 + (size_t)16*K, &sAl[l1]);
        GLOAD16(Bh  + boff + k0, &sBh[l0]); GLOAD16(Bh  + boff + k0 + (size_t)16*K, &sBh[l1]);
        GLOAD16(Blo + boff + k0, &sBl[l0]); GLOAD16(Blo + boff + k0 + (size_t)16*K, &sBl[l1]);
        __syncthreads();
        short8v afh[4], afl[4], bfh[4], bfl[4];
        #pragma unroll
        for (int mf = 0; mf < 4; ++mf) {
            int o = (wr + mf*16 + frow) * 32 + rchunk;
            afh[mf] = *(const short8v*)&sAh[o];
            afl[mf] = *(const short8v*)&sAl[o];
        }
        #pragma unroll
        for (int nf = 0; nf < 4; ++nf) {
            int o = (wc + nf*16 + frow) * 32 + rchunk;
            bfh[nf] = *(const short8v*)&sBh[o];
            bfl[nf] = *(const short8v*)&sBl[o];
        }
        #pragma unroll
        for (int mf = 0; mf < 4; ++mf)
            #pragma unroll
            for (int nf = 0; nf < 4; ++nf) {
                f32x4 a = acc[mf][nf];
                a = __builtin_amdgcn_mfma_f32_16x16x32_bf16(afl[mf], bfh[nf], a, 0, 0, 0);
                a = __builtin_amdgcn_mfma_f32_16x16x32_bf16(afh[mf], bfl[nf], a, 0, 0, 0);
                a = __builtin_amdgcn_mfma_f32_16x16x32_bf16(afh[mf], bfh[nf], a, 0, 0, 0);
                acc[mf][nf] = a;
            }
    }

    const int er = ((lane >> 4) << 2);
    const int ec = lane & 15;
    #pragma unroll
    for (int nf = 0; nf < 4; ++nf) {
        const int col = n0 + wc + nf*16 + ec;
        #pragma unroll
        for (int mf = 0; mf < 4; ++mf) {
            const int row = m0 + wr + mf*16 + er;
            #pragma unroll
            for (int r = 0; r < 4; ++r)
                C[(size_t)(row + r) * N + col] = acc[mf][nf][r];
        }
    }
}

// ---------------------------------------------------------------------------
// Flash attention with shifted relative logits (unchanged math; bf16 out).
// q/k live in fused [2048][1024] buffer (stride QKSTR).
// ---------------------------------------------------------------------------
#define QB 32
#define KB 64
#define RR 95      // KB + QB - 1
#define LPAD 68
#define SPAD 65

__global__ __launch_bounds__(256) void attn_kernel(
    const float* __restrict__ qs,   // stride QKSTR, pre-scaled by 1/8
    const float* __restrict__ ks,   // stride QKSTR
    const float* __restrict__ vs,   // [2048][1536]
    const float* __restrict__ relk, // [4096][512]
    const float* __restrict__ cbias,// [8][64]
    const float* __restrict__ pbias,// [8][64]
    unsigned short* __restrict__ o) // [2048][1536] bf16
{
    const int h  = blockIdx.x & (HEADS - 1);
    const int i0 = (blockIdx.x >> 3) * QB;

    __shared__ float qc[QB][LPAD];
    __shared__ float kt[KB][LPAD];
    __shared__ float rel[RR][LPAD];
    __shared__ float S[QB][SPAD];
    __shared__ float dlt[DKEY];
    __shared__ float red[QB][9];
    __shared__ float mrow[QB], lrow[QB], arow[QB];

    const int tid = threadIdx.x;

    if (tid < QB) { mrow[tid] = -INFINITY; lrow[tid] = 0.0f; }
    if (tid < DKEY) dlt[tid] = pbias[h*DKEY + tid] - cbias[h*DKEY + tid];
    for (int idx = tid; idx < QB * 16; idx += 256) {
        int r = idx >> 4, dq = (idx & 15) * 4;
        float4 qv = *(const float4*)(qs + (size_t)(i0 + r) * QKSTR + h*DKEY + dq);
        const float* cb = cbias + h*DKEY + dq;
        qv.x += cb[0]; qv.y += cb[1]; qv.z += cb[2]; qv.w += cb[3];
        *(float4*)&qc[r][dq] = qv;
    }

    const int ti = tid & 7;
    const int tj = tid >> 3;
    const int c  = tid & 63;
    const int rg = tid >> 6;

    float acc[8][3];
    #pragma unroll
    for (int ii = 0; ii < 8; ++ii) { acc[ii][0]=0.f; acc[ii][1]=0.f; acc[ii][2]=0.f; }

    for (int j0 = 0; j0 < SEQ; j0 += KB) {
        __syncthreads();
        for (int idx = tid; idx < KB * 16; idx += 256) {
            int r = idx >> 4, dq = (idx & 15) * 4;
            *(float4*)&kt[r][dq] =
                *(const float4*)(ks + (size_t)(j0 + r)*QKSTR + h*DKEY + dq);
        }
        int base = j0 - i0 + (SEQ - QB);
        for (int idx = tid; idx < RR * 16; idx += 256) {
            int r = idx >> 4, dq = (idx & 15) * 4;
            *(float4*)&rel[r][dq] =
                *(const float4*)(relk + (size_t)(base + r)*(HEADS*DKEY) + h*DKEY + dq);
        }
        __syncthreads();

        {
            float s[4][2];
            #pragma unroll
            for (int ii = 0; ii < 4; ++ii) { s[ii][0] = 0.f; s[ii][1] = 0.f; }
            const float* qrow[4];
            const float* krow[2];
            const float* rrow[4][2];
            #pragma unroll
            for (int ii = 0; ii < 4; ++ii) qrow[ii] = &qc[ti + 8*ii][0];
            #pragma unroll
            for (int jj = 0; jj < 2; ++jj) krow[jj] = &kt[2*tj + jj][0];
            #pragma unroll
            for (int ii = 0; ii < 4; ++ii)
                #pragma unroll
                for (int jj = 0; jj < 2; ++jj)
                    rrow[ii][jj] = &rel[(2*tj + jj) - (ti + 8*ii) + (QB - 1)][0];

            #pragma unroll 4
            for (int dq = 0; dq < DKEY; dq += 4) {
                float4 dv = *(const float4*)&dlt[dq];
                float4 qv[4], qp[4];
                #pragma unroll
                for (int ii = 0; ii < 4; ++ii) {
                    qv[ii] = *(const float4*)(qrow[ii] + dq);
                    qp[ii].x = qv[ii].x + dv.x; qp[ii].y = qv[ii].y + dv.y;
                    qp[ii].z = qv[ii].z + dv.z; qp[ii].w = qv[ii].w + dv.w;
                }
                float4 kv[2];
                kv[0] = *(const float4*)(krow[0] + dq);
                kv[1] = *(const float4*)(krow[1] + dq);
                #pragma unroll
                for (int ii = 0; ii < 4; ++ii)
                    #pragma unroll
                    for (int jj = 0; jj < 2; ++jj) {
                        float4 rv = *(const float4*)(rrow[ii][jj] + dq);
                        float t0 = s[ii][jj];
                        t0 = fmaf(qv[ii].x, kv[jj].x, t0);
                        t0 = fmaf(qv[ii].y, kv[jj].y, t0);
                        t0 = fmaf(qv[ii].z, kv[jj].z, t0);
                        t0 = fmaf(qv[ii].w, kv[jj].w, t0);
                        t0 = fmaf(qp[ii].x, rv.x, t0);
                        t0 = fmaf(qp[ii].y, rv.y, t0);
                        t0 = fmaf(qp[ii].z, rv.z, t0);
                        t0 = fmaf(qp[ii].w, rv.w, t0);
                        s[ii][jj] = t0;
                    }
            }
            #pragma unroll
            for (int ii = 0; ii < 4; ++ii)
                #pragma unroll
                for (int jj = 0; jj < 2; ++jj)
                    S[ti + 8*ii][2*tj + jj] = s[ii][jj];
        }
        __syncthreads();

        {
            int i = tid & 31, seg = tid >> 5;
            float mx = -INFINITY;
            #pragma unroll
            for (int j = 0; j < 8; ++j) mx = fmaxf(mx, S[i][seg*8 + j]);
            red[i][seg] = mx;
        }
        __syncthreads();
        if (tid < QB) {
            float mold = mrow[tid];
            float mx = mold;
            #pragma unroll
            for (int sg = 0; sg < 8; ++sg) mx = fmaxf(mx, red[tid][sg]);
            arow[tid] = (mold == -INFINITY) ? 0.0f : __expf(mold - mx);
            mrow[tid] = mx;
        }
        __syncthreads();
        {
            int i = tid & 31, seg = tid >> 5;
            float m = mrow[i];
            float sum = 0.0f;
            #pragma unroll
            for (int j = 0; j < 8; ++j) {
                float p = __expf(S[i][seg*8 + j] - m);
                S[i][seg*8 + j] = p;
                sum += p;
            }
            red[i][seg] = sum;
        }
        __syncthreads();
        if (tid < QB) {
            float sm = 0.0f;
            #pragma unroll
            for (int sg = 0; sg < 8; ++sg) sm += red[tid][sg];
            lrow[tid] = lrow[tid] * arow[tid] + sm;
        }
        {
            #pragma unroll
            for (int ii = 0; ii < 8; ++ii) {
                float a = arow[rg*8 + ii];
                acc[ii][0] *= a; acc[ii][1] *= a; acc[ii][2] *= a;
            }
            #pragma unroll 4
            for (int j = 0; j < KB; ++j) {
                const float* vp = vs + (size_t)(j0 + j)*(HEADS*DVAL) + h*DVAL + c;
                float v0 = vp[0], v1 = vp[64], v2 = vp[128];
                #pragma unroll
                for (int ii = 0; ii < 8; ++ii) {
                    float p = S[rg*8 + ii][j];
                    acc[ii][0] = fmaf(p, v0, acc[ii][0]);
                    acc[ii][1] = fmaf(p, v1, acc[ii][1]);
                    acc[ii][2] = fmaf(p, v2, acc[ii][2]);
                }
            }
        }
    }
    __syncthreads();
    #pragma unroll
    for (int ii = 0; ii < 8; ++ii) {
        float inv = 1.0f / lrow[rg*8 + ii];
        unsigned short* op = o + (size_t)(i0 + rg*8 + ii)*(HEADS*DVAL) + h*DVAL + c;
        op[0]   = f2bf(acc[ii][0] * inv);
        op[64]  = f2bf(acc[ii][1] * inv);
        op[128] = f2bf(acc[ii][2] * inv);
    }
}

// ---------------------------------------------------------------------------
extern "C" void kernel_launch(void* const* d_in, const int* in_sizes, int n_in,
                              void* d_out, int out_size, void* d_ws, size_t ws_size,
                              hipStream_t stream)
{
    const float* x     = (const float*)d_in[0];
    const float* Wq    = (const float*)d_in[1];
    const float* Wk    = (const float*)d_in[2];
    const float* Wv    = (const float*)d_in[3];
    const float* Wrel  = (const float*)d_in[4];
    const float* cbias = (const float*)d_in[5];
    const float* pbias = (const float*)d_in[6];
    const float* Wo    = (const float*)d_in[7];
    const float* bo    = (const float*)d_in[8];
    float* out = (float*)d_out;

    char* w = (char*)d_ws;
    auto alloc = [&](size_t bytes) {
        char* p = w; w += (bytes + 255) & ~(size_t)255; return p;
    };
    unsigned short* xhi   = (unsigned short*)alloc((size_t)SEQ*DIMM*2);   // -> ao later
    unsigned short* xlo   = (unsigned short*)alloc((size_t)SEQ*DIMM*2);
    unsigned short* wqk_h = (unsigned short*)alloc((size_t)1024*DIMM*2);  // [Wq;Wk] hi
    unsigned short* wqk_l = (unsigned short*)alloc((size_t)1024*DIMM*2);  // -> Wot later
    unsigned short* wvt   = (unsigned short*)alloc((size_t)DIMM*DIMM*2);
    unsigned short* wrelt = (unsigned short*)alloc((size_t)512*NREL*2);
    unsigned short* posb  = (unsigned short*)alloc((size_t)4096*NREL*2);
    float* qk   = (float*)alloc((size_t)SEQ*1024*4);
    float* v    = (float*)alloc((size_t)SEQ*DIMM*4);
    float* relk = (float*)alloc((size_t)4096*512*4);
    unsigned short* ao  = xhi;              // reuse (dead after v GEMM)
    unsigned short* wot = wqk_h;            // reuse (dead after qk GEMM)

    // 1. positional embedding (bf16, padded to 4096 rows)
    pos_embed_kernel<<<dim3(4096), dim3(64), 0, stream>>>(posb);
    // 2. casts
    cast_hilo<<<dim3(SEQ*DIMM/4/256), 256, 0, stream>>>(
        (const float4*)x, (ushort4v*)xhi, (ushort4v*)xlo, SEQ*DIMM/4);
    castT_kernel<<<dim3(512/32, DIMM/32), 256, 0, stream>>>(
        Wq, wqk_h, wqk_l, DIMM, 512, 0.125f);                 // scale folded in
    castT_kernel<<<dim3(512/32, DIMM/32), 256, 0, stream>>>(
        Wk, wqk_h + (size_t)512*DIMM, wqk_l + (size_t)512*DIMM, DIMM, 512, 1.0f);
    castT_kernel<<<dim3(DIMM/32, DIMM/32), 256, 0, stream>>>(
        Wv, wvt, nullptr, DIMM, DIMM, 1.0f);
    castT_kernel<<<dim3(512/32, NREL/32), 256, 0, stream>>>(
        Wrel, wrelt, nullptr, NREL, 512, 1.0f);
    // 3. projections (MFMA)
    gemm_bf16_split<<<dim3(1024/128, SEQ/128), 256, 0, stream>>>(
        xhi, xlo, wqk_h, wqk_l, qk, SEQ, 1024, DIMM);         // [q*0.125 | k]
    gemm_bf16<<<dim3(DIMM/128, SEQ/128), 256, 0, stream>>>(
        xhi, wvt, v, nullptr, SEQ, DIMM, DIMM);
    gemm_bf16<<<dim3(512/128, 4096/128), 256, 0, stream>>>(
        posb, wrelt, relk, nullptr, 4096, 512, NREL);
    // 4. Wo cast (after qk GEMM consumed wqk pool)
    castT_kernel<<<dim3(DIMM/32, DIMM/32), 256, 0, stream>>>(
        Wo, wot, nullptr, DIMM, DIMM, 1.0f);
    // 5. attention (ao reuses xhi region, dead after v GEMM)
    attn_kernel<<<dim3(HEADS * (SEQ/QB)), 256, 0, stream>>>(
        qk, qk + 512, v, relk, cbias, pbias, ao);
    // 6. output projection
    gemm_bf16<<<dim3(DIMM/128, SEQ/128), 256, 0, stream>>>(
        ao, wot, out, bo, SEQ, DIMM, DIMM);
}

// Round 4
// 294.500 us; speedup vs baseline: 4.1392x; 2.3542x over previous
//
#include <hip/hip_runtime.h>
#include <math.h>

#define HEADS 8
#define DKEY 64
#define DVAL 192
#define SEQ 2048
#define DIMM 1536
#define NREL 192
#define NB 32
#define TDIST (2*SEQ-1)   // 4095
#define QKSTR 1024        // row stride of fused [q|k] buffer

typedef __attribute__((ext_vector_type(8))) short short8v;   // bf16x8 MFMA frag
typedef __attribute__((ext_vector_type(4))) float f32x4;
typedef __attribute__((ext_vector_type(4))) unsigned short ushort4v;

__device__ __forceinline__ unsigned short f2bf(float f) {
    unsigned int u = __float_as_uint(f);
    u += 0x7FFFu + ((u >> 16) & 1u);          // RNE
    return (unsigned short)(u >> 16);
}
__device__ __forceinline__ float bf2f(unsigned short h) {
    return __uint_as_float(((unsigned int)h) << 16);
}

#define GLOAD16(gp, lp) __builtin_amdgcn_global_load_lds( \
    (const __attribute__((address_space(1))) void*)(gp),  \
    (__attribute__((address_space(3))) void*)(lp), 16, 0, 0)

// ---------------------------------------------------------------------------
// Positional embedding -> bf16 [4096][192]; row 4095 zeroed (pad row).
// ---------------------------------------------------------------------------
__global__ void pos_embed_kernel(unsigned short* __restrict__ posb) {
    int t = blockIdx.x;           // 0..4095
    int f = threadIdx.x;
    if (f >= NB) return;
    unsigned short* row = posb + (size_t)t * NREL;
    if (t >= TDIST) {             // pad row: zeros
        row[f] = 0; row[NB+f] = 0; row[2*NB+f] = 0;
        row[96+f] = 0; row[96+NB+f] = 0; row[96+2*NB+f] = 0;
        return;
    }
    float dist = (float)(t - (SEQ - 1));
    float absd = fabsf(dist);
    float sgn  = (dist > 0.0f) ? 1.0f : ((dist < 0.0f) ? -1.0f : 0.0f);
    float hl = exp2f(3.0f + 8.0f * (float)f / 31.0f);
    float e = exp2f(-absd / hl);
    float cw = exp2f((float)(f + 1)) - 1.0f;
    float c = (cw > absd) ? 1.0f : 0.0f;
    // xlogy(conc-1, absd): first arg > 0 always, so absd==0 gives -inf
    double conc = (double)(4 * (f + 1) * (f + 1));
    double rate = ((double)(f + 1)) / 16.0;
    double lu = (absd > 0.0f)
        ? ((conc - 1.0) * log((double)absd) - rate * (double)absd)
        : -INFINITY;
    double ln = lgamma(conc) - conc * log(rate);
    float g = (float)exp(lu - ln) + 1e-8f;
    float gm = g;
    #pragma unroll
    for (int off = 16; off >= 1; off >>= 1)
        gm = fmaxf(gm, __shfl_xor(gm, off, 32));
    g = g / gm;
    row[f]           = f2bf(e);
    row[NB + f]      = f2bf(c);
    row[2*NB + f]    = f2bf(g);
    row[96 + f]      = f2bf(sgn * e);
    row[96 + NB + f] = f2bf(sgn * c);
    row[96 + 2*NB+f] = f2bf(sgn * g);
}

// ---------------------------------------------------------------------------
// x f32 -> hi/lo bf16 split
// ---------------------------------------------------------------------------
__global__ __launch_bounds__(256) void cast_hilo(
    const float4* __restrict__ in, ushort4v* __restrict__ hi,
    ushort4v* __restrict__ lo, int n4)
{
    int i = blockIdx.x * 256 + threadIdx.x;
    if (i >= n4) return;
    float4 v = in[i];
    unsigned short h0 = f2bf(v.x), h1 = f2bf(v.y), h2 = f2bf(v.z), h3 = f2bf(v.w);
    hi[i] = (ushort4v){h0, h1, h2, h3};
    lo[i] = (ushort4v){ f2bf(v.x - bf2f(h0)), f2bf(v.y - bf2f(h1)),
                        f2bf(v.z - bf2f(h2)), f2bf(v.w - bf2f(h3)) };
}

// ---------------------------------------------------------------------------
// W f32 [R][C] -> hiT (,loT) bf16 [C][R], optionally pre-scaled.
// ---------------------------------------------------------------------------
__global__ __launch_bounds__(256) void castT_kernel(
    const float* __restrict__ in, unsigned short* __restrict__ hiT,
    unsigned short* __restrict__ loT, int R, int C, float scale)
{
    __shared__ float t[32][33];
    int c0 = blockIdx.x * 32, r0 = blockIdx.y * 32;
    int tx = threadIdx.x & 31, ty = threadIdx.x >> 5;
    #pragma unroll
    for (int rr = ty; rr < 32; rr += 8)
        t[rr][tx] = in[(size_t)(r0 + rr) * C + c0 + tx] * scale;
    __syncthreads();
    #pragma unroll
    for (int cc = ty; cc < 32; cc += 8) {
        float v = t[tx][cc];
        unsigned short h = f2bf(v);
        size_t oi = (size_t)(c0 + cc) * R + r0 + tx;
        hiT[oi] = h;
        if (loT) loT[oi] = f2bf(v - bf2f(h));
    }
}

// ---------------------------------------------------------------------------
// f32 [R][C] -> bf16 transposed [C][R]
// ---------------------------------------------------------------------------
__global__ __launch_bounds__(256) void transpose_cast(
    const float* __restrict__ in, unsigned short* __restrict__ outT,
    int R, int C)
{
    __shared__ float t[32][33];
    int c0 = blockIdx.x * 32, r0 = blockIdx.y * 32;
    int tx = threadIdx.x & 31, ty = threadIdx.x >> 5;
    #pragma unroll
    for (int rr = ty; rr < 32; rr += 8)
        t[rr][tx] = in[(size_t)(r0 + rr) * C + c0 + tx];
    __syncthreads();
    #pragma unroll
    for (int cc = ty; cc < 32; cc += 8)
        outT[(size_t)(c0 + cc) * R + r0 + tx] = f2bf(t[tx][cc]);
}

// ---------------------------------------------------------------------------
// qk f32 [2048][1024] -> qc hi/lo (+cbias), qp (+pbias), k hi/lo, all
// per-head [8][2048][64] bf16.
// ---------------------------------------------------------------------------
__global__ __launch_bounds__(256) void qk_cast(
    const float* __restrict__ qk, const float* __restrict__ cbias,
    const float* __restrict__ pbias,
    unsigned short* __restrict__ qchi, unsigned short* __restrict__ qclo,
    unsigned short* __restrict__ qpb, unsigned short* __restrict__ khi,
    unsigned short* __restrict__ klo)
{
    int id = blockIdx.x * 256 + threadIdx.x;      // [0, 8*2048*16)
    int d4 = (id & 15) * 4;
    int i  = (id >> 4) & 2047;
    int h  = id >> 15;
    float4 qv = *(const float4*)(qk + (size_t)i*QKSTR + h*64 + d4);
    float4 kv = *(const float4*)(qk + (size_t)i*QKSTR + 512 + h*64 + d4);
    float4 cb = *(const float4*)(cbias + h*64 + d4);
    float4 pb = *(const float4*)(pbias + h*64 + d4);
    float qc[4] = {qv.x+cb.x, qv.y+cb.y, qv.z+cb.z, qv.w+cb.w};
    float qp[4] = {qv.x+pb.x, qv.y+pb.y, qv.z+pb.z, qv.w+pb.w};
    float kk[4] = {kv.x, kv.y, kv.z, kv.w};
    ushort4v a, b, c2, d, e;
    #pragma unroll
    for (int j = 0; j < 4; ++j) {
        a[j] = f2bf(qc[j]); b[j] = f2bf(qc[j] - bf2f(a[j]));
        c2[j] = f2bf(qp[j]);
        d[j] = f2bf(kk[j]); e[j] = f2bf(kk[j] - bf2f(d[j]));
    }
    size_t o = (((size_t)h*2048 + i)*64 + d4) >> 2;
    ((ushort4v*)qchi)[o] = a; ((ushort4v*)qclo)[o] = b;
    ((ushort4v*)qpb)[o] = c2; ((ushort4v*)khi)[o] = d; ((ushort4v*)klo)[o] = e;
}

// ---------------------------------------------------------------------------
// relk f32 [4096][512] -> relb [8][4096][64] bf16
// ---------------------------------------------------------------------------
__global__ __launch_bounds__(256) void rel_cast(
    const float* __restrict__ relk, unsigned short* __restrict__ relb)
{
    int id = blockIdx.x * 256 + threadIdx.x;      // [0, 8*4096*16)
    int d4 = (id & 15) * 4;
    int t  = (id >> 4) & 4095;
    int h  = id >> 16;
    float4 v = *(const float4*)(relk + (size_t)t*512 + h*64 + d4);
    ushort4v u = { f2bf(v.x), f2bf(v.y), f2bf(v.z), f2bf(v.w) };
    ((ushort4v*)relb)[(((size_t)h*4096 + t)*64 + d4) >> 2] = u;
}

// ---------------------------------------------------------------------------
// bf16 MFMA GEMM (unchanged from round 3): C = A @ Bt^T (+bias)
// ---------------------------------------------------------------------------
__global__ __launch_bounds__(256) void gemm_bf16(
    const unsigned short* __restrict__ A, const unsigned short* __restrict__ Bt,
    float* __restrict__ C, const float* __restrict__ bias,
    int M, int N, int K)
{
    __shared__ unsigned short Als[128 * 32];
    __shared__ unsigned short Bls[128 * 32];
    const int tid  = threadIdx.x;
    const int lane = tid & 63;
    const int wave = tid >> 6;
    const int wr = (wave >> 1) * 64, wc = (wave & 1) * 64;
    const int m0 = blockIdx.y * 128, n0 = blockIdx.x * 128;

    const int sr = lane >> 2;
    const int sc = (((lane & 3) ^ ((lane >> 4) & 3))) * 8;
    const unsigned short* gA0 = A  + (size_t)(m0 + wave*32 + sr) * K + sc;
    const unsigned short* gB0 = Bt + (size_t)(n0 + wave*32 + sr) * K + sc;
    unsigned short* lA0 = &Als[(wave*32) * 32];
    unsigned short* lA1 = &Als[(wave*32 + 16) * 32];
    unsigned short* lB0 = &Bls[(wave*32) * 32];
    unsigned short* lB1 = &Bls[(wave*32 + 16) * 32];

    const int frow = lane & 15;
    const int rchunk = (((lane >> 4) ^ ((frow >> 2) & 3))) * 8;

    f32x4 acc[4][4] = {};

    for (int k0 = 0; k0 < K; k0 += 32) {
        __syncthreads();
        GLOAD16(gA0 + k0, lA0);
        GLOAD16(gA0 + k0 + (size_t)16 * K, lA1);
        GLOAD16(gB0 + k0, lB0);
        GLOAD16(gB0 + k0 + (size_t)16 * K, lB1);
        __syncthreads();
        short8v af[4], bf[4];
        #pragma unroll
        for (int mf = 0; mf < 4; ++mf)
            af[mf] = *(const short8v*)&Als[(wr + mf*16 + frow) * 32 + rchunk];
        #pragma unroll
        for (int nf = 0; nf < 4; ++nf)
            bf[nf] = *(const short8v*)&Bls[(wc + nf*16 + frow) * 32 + rchunk];
        #pragma unroll
        for (int mf = 0; mf < 4; ++mf)
            #pragma unroll
            for (int nf = 0; nf < 4; ++nf)
                acc[mf][nf] = __builtin_amdgcn_mfma_f32_16x16x32_bf16(
                    af[mf], bf[nf], acc[mf][nf], 0, 0, 0);
    }

    const int er = ((lane >> 4) << 2);
    const int ec = lane & 15;
    #pragma unroll
    for (int nf = 0; nf < 4; ++nf) {
        const int col = n0 + wc + nf*16 + ec;
        const float bv = bias ? bias[col] : 0.0f;
        #pragma unroll
        for (int mf = 0; mf < 4; ++mf) {
            const int row = m0 + wr + mf*16 + er;
            #pragma unroll
            for (int r = 0; r < 4; ++r)
                C[(size_t)(row + r) * N + col] = acc[mf][nf][r] + bv;
        }
    }
}

// ---------------------------------------------------------------------------
// Split-precision bf16 GEMM (unchanged from round 3)
// ---------------------------------------------------------------------------
__global__ __launch_bounds__(256) void gemm_bf16_split(
    const unsigned short* __restrict__ Ah, const unsigned short* __restrict__ Alo,
    const unsigned short* __restrict__ Bh, const unsigned short* __restrict__ Blo,
    float* __restrict__ C, int M, int N, int K)
{
    __shared__ unsigned short sAh[128*32], sAl[128*32], sBh[128*32], sBl[128*32];
    const int tid  = threadIdx.x;
    const int lane = tid & 63;
    const int wave = tid >> 6;
    const int wr = (wave >> 1) * 64, wc = (wave & 1) * 64;
    const int m0 = blockIdx.y * 128, n0 = blockIdx.x * 128;

    const int sr = lane >> 2;
    const int sc = (((lane & 3) ^ ((lane >> 4) & 3))) * 8;
    const size_t aoff = (size_t)(m0 + wave*32 + sr) * K + sc;
    const size_t boff = (size_t)(n0 + wave*32 + sr) * K + sc;
    const int l0 = (wave*32) * 32, l1 = (wave*32 + 16) * 32;

    const int frow = lane & 15;
    const int rchunk = (((lane >> 4) ^ ((frow >> 2) & 3))) * 8;

    f32x4 acc[4][4] = {};

    for (int k0 = 0; k0 < K; k0 += 32) {
        __syncthreads();
        GLOAD16(Ah  + aoff + k0, &sAh[l0]); GLOAD16(Ah  + aoff + k0 + (size_t)16*K, &sAh[l1]);
        GLOAD16(Alo + aoff + k0, &sAl[l0]); GLOAD16(Alo + aoff + k0 + (size_t)16*K, &sAl[l1]);
        GLOAD16(Bh  + boff + k0, &sBh[l0]); GLOAD16(Bh  + boff + k0 + (size_t)16*K, &sBh[l1]);
        GLOAD16(Blo + boff + k0, &sBl[l0]); GLOAD16(Blo + boff + k0 + (size_t)16*K, &sBl[l1]);
        __syncthreads();
        short8v afh[4], afl[4], bfh[4], bfl[4];
        #pragma unroll
        for (int mf = 0; mf < 4; ++mf) {
            int o = (wr + mf*16 + frow) * 32 + rchunk;
            afh[mf] = *(const short8v*)&sAh[o];
            afl[mf] = *(const short8v*)&sAl[o];
        }
        #pragma unroll
        for (int nf = 0; nf < 4; ++nf) {
            int o = (wc + nf*16 + frow) * 32 + rchunk;
            bfh[nf] = *(const short8v*)&sBh[o];
            bfl[nf] = *(const short8v*)&sBl[o];
        }
        #pragma unroll
        for (int mf = 0; mf < 4; ++mf)
            #pragma unroll
            for (int nf = 0; nf < 4; ++nf) {
                f32x4 a = acc[mf][nf];
                a = __builtin_amdgcn_mfma_f32_16x16x32_bf16(afl[mf], bfh[nf], a, 0, 0, 0);
                a = __builtin_amdgcn_mfma_f32_16x16x32_bf16(afh[mf], bfl[nf], a, 0, 0, 0);
                a = __builtin_amdgcn_mfma_f32_16x16x32_bf16(afh[mf], bfh[nf], a, 0, 0, 0);
                acc[mf][nf] = a;
            }
    }

    const int er = ((lane >> 4) << 2);
    const int ec = lane & 15;
    #pragma unroll
    for (int nf = 0; nf < 4; ++nf) {
        const int col = n0 + wc + nf*16 + ec;
        #pragma unroll
        for (int mf = 0; mf < 4; ++mf) {
            const int row = m0 + wr + mf*16 + er;
            #pragma unroll
            for (int r = 0; r < 4; ++r)
                C[(size_t)(row + r) * N + col] = acc[mf][nf][r];
        }
    }
}

// ---------------------------------------------------------------------------
// MFMA flash attention with banded relative logits.
// Block = (head, 32 q-rows); 4 waves as (wq: 16-row group) x (wj: 32-col half).
// S = qc.k (split bf16: 3 MFMA passes) + gather(qp @ rel_band^T).
// Gather: R[m][c], c = j_local - m + 15, via ds_bpermute within 16-lane group.
// ---------------------------------------------------------------------------
#define QB 32
#define KB 64

__global__ __launch_bounds__(256, 2) void attn_mfma(
    const unsigned short* __restrict__ qchi,  // [8][2048][64]
    const unsigned short* __restrict__ qclo,
    const unsigned short* __restrict__ qpb,
    const unsigned short* __restrict__ kghi,  // [8][2048][64]
    const unsigned short* __restrict__ kglo,
    const unsigned short* __restrict__ vtg,   // [1536][2048] = [8][192][2048]
    const unsigned short* __restrict__ relb,  // [8][4096][64]
    unsigned short* __restrict__ o)           // [2048][1536] bf16
{
    __shared__ __align__(16) unsigned short skhi[64*64];
    __shared__ __align__(16) unsigned short sklo[64*64];
    __shared__ __align__(16) unsigned short svt[192*64];
    __shared__ __align__(16) unsigned short srel[96*64];
    __shared__ __align__(16) unsigned short sP[2][16*64];
    __shared__ float redm[2][2][16];
    __shared__ float reds[2][2][16];

    const int tid = threadIdx.x;
    const int h  = blockIdx.x & 7;
    const int i0 = (blockIdx.x >> 3) * QB;
    const int lane = tid & 63;
    const int wave = tid >> 6;
    const int wq = wave >> 1, wj = wave & 1;
    const int l15 = lane & 15, lg = lane >> 4;

    // Q fragments, direct from global (rows i0 + wq*16 + l15)
    const size_t qrow = ((size_t)h*2048 + i0 + wq*16 + l15) * 64;
    short8v fqh[2], fql[2], fqp[2];
    #pragma unroll
    for (int kh = 0; kh < 2; ++kh) {
        fqh[kh] = *(const short8v*)(qchi + qrow + kh*32 + lg*8);
        fql[kh] = *(const short8v*)(qclo + qrow + kh*32 + lg*8);
        fqp[kh] = *(const short8v*)(qpb  + qrow + kh*32 + lg*8);
    }

    float mrow[4], lrow[4];
    #pragma unroll
    for (int r = 0; r < 4; ++r) { mrow[r] = -INFINITY; lrow[r] = 0.0f; }
    f32x4 acc[6] = {};                        // v-cols wj*96 + nf*16 + l15

    const int offw = 16 - wq*16 + wj*32;      // wave's rel window start

    for (int j0 = 0; j0 < SEQ; j0 += KB) {
        __syncthreads();                      // (A) prev tile LDS reads done
        // ---- stage k hi/lo [64][64], rel [96][64], vT [192][64] ----
        {
            const size_t kbase = ((size_t)h*2048 + j0) * 64;
            #pragma unroll
            for (int it = 0; it < 2; ++it) {
                int u = it*256 + tid; int row = u >> 3;
                int sch = (u & 7) ^ (row & 7);
                GLOAD16(kghi + kbase + row*64 + sch*8, &skhi[(it*256 + wave*64)*8]);
                GLOAD16(kglo + kbase + row*64 + sch*8, &sklo[(it*256 + wave*64)*8]);
            }
            const int t0 = j0 - i0 + 2016;    // band start, always in [0,3968]
            const size_t rbase = ((size_t)h*4096 + t0) * 64;
            #pragma unroll
            for (int it = 0; it < 3; ++it) {
                int u = it*256 + tid; int row = u >> 3;
                int sch = (u & 7) ^ (row & 7);
                GLOAD16(relb + rbase + row*64 + sch*8, &srel[(it*256 + wave*64)*8]);
            }
            #pragma unroll
            for (int it = 0; it < 6; ++it) {
                int u = it*256 + tid; int n = u >> 3;
                int sch = (u & 7) ^ (n & 7);
                GLOAD16(vtg + ((size_t)(h*192 + n))*2048 + j0 + sch*8,
                        &svt[(it*256 + wave*64)*8]);
            }
        }
        __syncthreads();                      // (B) staging complete

        // ---- content logits (split bf16) ----
        f32x4 sc[2] = {};
        #pragma unroll
        for (int nf = 0; nf < 2; ++nf) {
            int row = wj*32 + nf*16 + l15;
            #pragma unroll
            for (int kh = 0; kh < 2; ++kh) {
                int c = (kh*4 + lg) ^ (row & 7);
                short8v bh = *(const short8v*)&skhi[row*64 + c*8];
                short8v bl = *(const short8v*)&sklo[row*64 + c*8];
                sc[nf] = __builtin_amdgcn_mfma_f32_16x16x32_bf16(fql[kh], bh, sc[nf],0,0,0);
                sc[nf] = __builtin_amdgcn_mfma_f32_16x16x32_bf16(fqh[kh], bl, sc[nf],0,0,0);
                sc[nf] = __builtin_amdgcn_mfma_f32_16x16x32_bf16(fqh[kh], bh, sc[nf],0,0,0);
            }
        }
        // ---- rel band logits ----
        f32x4 R[3] = {};
        #pragma unroll
        for (int cf = 0; cf < 3; ++cf) {
            int row = offw + cf*16 + l15;
            #pragma unroll
            for (int kh = 0; kh < 2; ++kh) {
                int c = (kh*4 + lg) ^ (row & 7);
                short8v br = *(const short8v*)&srel[row*64 + c*8];
                R[cf] = __builtin_amdgcn_mfma_f32_16x16x32_bf16(fqp[kh], br, R[cf],0,0,0);
            }
        }
        // ---- diagonal gather: S_rel[m][j_local] = R[m][j_local - m + 15] ----
        float S[2][4];
        #pragma unroll
        for (int r = 0; r < 4; ++r) {
            int m = lg*4 + r;
            int t = l15 + 15 - m;                  // 0..30
            int idx = (((lane & 48) | (t & 15))) << 2;
            float g0 = __uint_as_float((unsigned)__builtin_amdgcn_ds_bpermute(idx, (int)__float_as_uint(R[0][r])));
            float g1 = __uint_as_float((unsigned)__builtin_amdgcn_ds_bpermute(idx, (int)__float_as_uint(R[1][r])));
            float g2 = __uint_as_float((unsigned)__builtin_amdgcn_ds_bpermute(idx, (int)__float_as_uint(R[2][r])));
            bool cross = (t >= 16);
            S[0][r] = sc[0][r] + (cross ? g1 : g0);
            S[1][r] = sc[1][r] + (cross ? g2 : g1);
        }
        // ---- online softmax ----
        float tmax[4];
        #pragma unroll
        for (int r = 0; r < 4; ++r) {
            float mx = fmaxf(S[0][r], S[1][r]);
            mx = fmaxf(mx, __shfl_xor(mx, 1));
            mx = fmaxf(mx, __shfl_xor(mx, 2));
            mx = fmaxf(mx, __shfl_xor(mx, 4));
            mx = fmaxf(mx, __shfl_xor(mx, 8));
            tmax[r] = mx;
        }
        if (l15 == 0) {
            #pragma unroll
            for (int r = 0; r < 4; ++r) redm[wq][wj][lg*4 + r] = tmax[r];
        }
        __syncthreads();                      // (C) redm visible
        float alpha[4], p[2][4], tsum[4];
        #pragma unroll
        for (int r = 0; r < 4; ++r) {
            int m = lg*4 + r;
            float nm = fmaxf(mrow[r], fmaxf(redm[wq][0][m], redm[wq][1][m]));
            alpha[r] = __expf(mrow[r] - nm);
            mrow[r] = nm;
            p[0][r] = __expf(S[0][r] - nm);
            p[1][r] = __expf(S[1][r] - nm);
            float s = p[0][r] + p[1][r];
            s += __shfl_xor(s, 1); s += __shfl_xor(s, 2);
            s += __shfl_xor(s, 4); s += __shfl_xor(s, 8);
            tsum[r] = s;
        }
        if (l15 == 0) {
            #pragma unroll
            for (int r = 0; r < 4; ++r) reds[wq][wj][lg*4 + r] = tsum[r];
        }
        #pragma unroll
        for (int nf = 0; nf < 2; ++nf) {
            int jc = wj*32 + nf*16 + l15;
            #pragma unroll
            for (int r = 0; r < 4; ++r) {
                int m = lg*4 + r;
                sP[wq][m*64 + ((jc>>3) ^ (m&7))*8 + (jc&7)] = f2bf(p[nf][r]);
            }
        }
        #pragma unroll
        for (int nf = 0; nf < 6; ++nf)
            #pragma unroll
            for (int r = 0; r < 4; ++r) acc[nf][r] *= alpha[r];
        __syncthreads();                      // (D) reds + sP visible
        #pragma unroll
        for (int r = 0; r < 4; ++r) {
            int m = lg*4 + r;
            lrow[r] = lrow[r]*alpha[r] + reds[wq][0][m] + reds[wq][1][m];
        }
        // ---- PV ----
        short8v pa[2];
        #pragma unroll
        for (int kh = 0; kh < 2; ++kh) {
            int c = (kh*4 + lg) ^ (l15 & 7);
            pa[kh] = *(const short8v*)&sP[wq][l15*64 + c*8];
        }
        #pragma unroll
        for (int nf = 0; nf < 6; ++nf) {
            int n = wj*96 + nf*16 + l15;
            #pragma unroll
            for (int kh = 0; kh < 2; ++kh) {
                int c = (kh*4 + lg) ^ (n & 7);
                short8v bv = *(const short8v*)&svt[n*64 + c*8];
                acc[nf] = __builtin_amdgcn_mfma_f32_16x16x32_bf16(pa[kh], bv, acc[nf],0,0,0);
            }
        }
    }
    // ---- epilogue ----
    #pragma unroll
    for (int nf = 0; nf < 6; ++nf) {
        int col = h*192 + wj*96 + nf*16 + l15;
        #pragma unroll
        for (int r = 0; r < 4; ++r) {
            int i = i0 + wq*16 + lg*4 + r;
            o[(size_t)i*1536 + col] = f2bf(acc[nf][r] / lrow[r]);
        }
    }
}

// ---------------------------------------------------------------------------
extern "C" void kernel_launch(void* const* d_in, const int* in_sizes, int n_in,
                              void* d_out, int out_size, void* d_ws, size_t ws_size,
                              hipStream_t stream)
{
    const float* x     = (const float*)d_in[0];
    const float* Wq    = (const float*)d_in[1];
    const float* Wk    = (const float*)d_in[2];
    const float* Wv    = (const float*)d_in[3];
    const float* Wrel  = (const float*)d_in[4];
    const float* cbias = (const float*)d_in[5];
    const float* pbias = (const float*)d_in[6];
    const float* Wo    = (const float*)d_in[7];
    const float* bo    = (const float*)d_in[8];
    float* out = (float*)d_out;

    char* w = (char*)d_ws;
    auto alloc = [&](size_t bytes) {
        char* p = w; w += (bytes + 255) & ~(size_t)255; return p;
    };
    unsigned short* xhi   = (unsigned short*)alloc((size_t)SEQ*DIMM*2);   // 6.29MB
    unsigned short* xlo   = (unsigned short*)alloc((size_t)SEQ*DIMM*2);   // 6.29MB
    unsigned short* wqk_h = (unsigned short*)alloc((size_t)1024*DIMM*2);  // 3.1MB
    unsigned short* wqk_l = (unsigned short*)alloc((size_t)1024*DIMM*2);
    unsigned short* wvt   = (unsigned short*)alloc((size_t)DIMM*DIMM*2);  // 4.7MB
    unsigned short* wrelt = (unsigned short*)alloc((size_t)512*NREL*2);
    unsigned short* posb  = (unsigned short*)alloc((size_t)4096*NREL*2);
    float* qk   = (float*)alloc((size_t)SEQ*1024*4);                      // 8.4MB
    float* v    = (float*)alloc((size_t)SEQ*DIMM*4);                      // 12.6MB
    float* relk = (float*)alloc((size_t)4096*512*4);                      // 8.4MB
    unsigned short* relb = (unsigned short*)alloc((size_t)8*4096*64*2);   // 4.2MB
    // overlays (dead-after analysis):
    unsigned short* ao   = xhi;                         // xhi dead after v GEMM
    unsigned short* wot  = wqk_h;                       // dead after qk GEMM
    unsigned short* qchi = xlo;                         // xlo dead after qk GEMM
    unsigned short* qclo = xlo + (size_t)8*2048*64;
    unsigned short* qpb  = xlo + (size_t)16*2048*64;    // 3*2.1MB = 6.29MB exact
    unsigned short* khi  = wvt;                         // wvt dead after v GEMM
    unsigned short* klo  = wvt + (size_t)8*2048*64;     // 4.2 <= 4.7MB
    unsigned short* vt   = (unsigned short*)qk;         // qk dead after qk_cast

    // 1. positional embedding (bf16, padded to 4096 rows)
    pos_embed_kernel<<<dim3(4096), dim3(64), 0, stream>>>(posb);
    // 2. casts
    cast_hilo<<<dim3(SEQ*DIMM/4/256), 256, 0, stream>>>(
        (const float4*)x, (ushort4v*)xhi, (ushort4v*)xlo, SEQ*DIMM/4);
    castT_kernel<<<dim3(512/32, DIMM/32), 256, 0, stream>>>(
        Wq, wqk_h, wqk_l, DIMM, 512, 0.125f);
    castT_kernel<<<dim3(512/32, DIMM/32), 256, 0, stream>>>(
        Wk, wqk_h + (size_t)512*DIMM, wqk_l + (size_t)512*DIMM, DIMM, 512, 1.0f);
    castT_kernel<<<dim3(DIMM/32, DIMM/32), 256, 0, stream>>>(
        Wv, wvt, nullptr, DIMM, DIMM, 1.0f);
    castT_kernel<<<dim3(512/32, NREL/32), 256, 0, stream>>>(
        Wrel, wrelt, nullptr, NREL, 512, 1.0f);
    // 3. projections (MFMA)
    gemm_bf16_split<<<dim3(1024/128, SEQ/128), 256, 0, stream>>>(
        xhi, xlo, wqk_h, wqk_l, qk, SEQ, 1024, DIMM);         // [q*0.125 | k]
    gemm_bf16<<<dim3(DIMM/128, SEQ/128), 256, 0, stream>>>(
        xhi, wvt, v, nullptr, SEQ, DIMM, DIMM);
    gemm_bf16<<<dim3(512/128, 4096/128), 256, 0, stream>>>(
        posb, wrelt, relk, nullptr, 4096, 512, NREL);
    // 4. Wo cast (into wqk_h; qk GEMM already consumed it)
    castT_kernel<<<dim3(DIMM/32, DIMM/32), 256, 0, stream>>>(
        Wo, wot, nullptr, DIMM, DIMM, 1.0f);
    // 5. attention operand casts
    qk_cast<<<dim3(8*2048*16/256), 256, 0, stream>>>(
        qk, cbias, pbias, qchi, qclo, qpb, khi, klo);
    transpose_cast<<<dim3(DIMM/32, SEQ/32), 256, 0, stream>>>(
        v, vt, SEQ, DIMM);                                    // after qk_cast!
    rel_cast<<<dim3(8*4096*16/256), 256, 0, stream>>>(relk, relb);
    // 6. MFMA flash attention
    attn_mfma<<<dim3(HEADS * (SEQ/QB)), 256, 0, stream>>>(
        qchi, qclo, qpb, khi, klo, vt, relb, ao);
    // 7. output projection
    gemm_bf16<<<dim3(DIMM/128, SEQ/128), 256, 0, stream>>>(
        ao, wot, out, bo, SEQ, DIMM, DIMM);
}